// Round 1
// baseline (440.782 us; speedup 1.0000x reference)
//
#include <hip/hip_runtime.h>

#define D_DIM 1024
#define B_DIM 128
#define C_DIM 1000
#define EPSF 1e-6f

// P[m,n] = sum_k A[m,k] * tril(L)[k,n]   (tril: L[k,n] used only when k >= n)
// Triangular K-skip: for column tile starting at n0, k < n0 contributes nothing.
template<int BM, int BN, int BK>
__global__ void gemm_tril(const float* __restrict__ A, const float* __restrict__ L,
                          float* __restrict__ P, int M) {
    __shared__ float As[BK][BM + 4];   // +4: keep 16B alignment for b128 reads
    __shared__ float Ls[BK][BN + 4];
    const int tid = threadIdx.x;               // 256 threads
    const int tx = tid & 15, ty = tid >> 4;    // 16 x 16
    const int m0 = blockIdx.y * BM, n0 = blockIdx.x * BN;
    float acc[4][4] = {};

    for (int k0 = n0; k0 < D_DIM; k0 += BK) {  // start at n0: triangular skip
        for (int i = tid; i < BM * BK; i += 256) {
            int mm = i / BK, kk = i % BK;
            int m = m0 + mm;
            As[kk][mm] = (m < M) ? A[m * D_DIM + k0 + kk] : 0.f;
        }
        for (int i = tid; i < BK * BN; i += 256) {
            int kk = i / BN, nn = i % BN;
            int d = k0 + kk, f = n0 + nn;
            Ls[kk][nn] = (d >= f) ? L[d * D_DIM + f] : 0.f;  // tril mask
        }
        __syncthreads();
#pragma unroll
        for (int kk = 0; kk < BK; ++kk) {
            float a[4], b[4];
#pragma unroll
            for (int i = 0; i < 4; ++i) a[i] = As[kk][ty * 4 + i];
#pragma unroll
            for (int j = 0; j < 4; ++j) b[j] = Ls[kk][tx * 4 + j];
#pragma unroll
            for (int i = 0; i < 4; ++i)
#pragma unroll
                for (int j = 0; j < 4; ++j)
                    acc[i][j] = fmaf(a[i], b[j], acc[i][j]);
        }
        __syncthreads();
    }
#pragma unroll
    for (int i = 0; i < 4; ++i) {
        int m = m0 + ty * 4 + i;
        if (m < M) {
#pragma unroll
            for (int j = 0; j < 4; ++j)
                P[m * D_DIM + n0 + tx * 4 + j] = acc[i][j];
        }
    }
}

// Per row m: nrm[m] = ||P_m||^2 + eps*||A_m||^2 ;  bdot[m] = beta . A_m
__global__ void row_aux(const float* __restrict__ A, const float* __restrict__ P,
                        const float* __restrict__ beta,
                        float* __restrict__ nrm, float* __restrict__ bdot) {
    const int m = blockIdx.x;
    const int tid = threadIdx.x;   // 256
    float sp = 0.f, sa = 0.f, sb = 0.f;
    for (int d = tid; d < D_DIM; d += 256) {
        float a = A[m * D_DIM + d];
        float p = P[m * D_DIM + d];
        sp = fmaf(p, p, sp);
        sa = fmaf(a, a, sa);
        sb = fmaf(beta[d], a, sb);
    }
#pragma unroll
    for (int off = 32; off > 0; off >>= 1) {
        sp += __shfl_down(sp, off);
        sa += __shfl_down(sa, off);
        sb += __shfl_down(sb, off);
    }
    __shared__ float red[3][4];
    int lane = tid & 63, wid = tid >> 6;
    if (lane == 0) { red[0][wid] = sp; red[1][wid] = sa; red[2][wid] = sb; }
    __syncthreads();
    if (tid == 0) {
        float p = red[0][0] + red[0][1] + red[0][2] + red[0][3];
        float a = red[1][0] + red[1][1] + red[1][2] + red[1][3];
        float b = red[2][0] + red[2][1] + red[2][2] + red[2][3];
        nrm[m]  = fmaf(EPSF, a, p);
        bdot[m] = b;
    }
}

// out[b,c] = -scale * ( sqrt(nx[b] + nmu[c] - 2*u_b.v_c + eps)
//                       + lmbda * sqrt((bx[b]-bmu[c])^2 + eps) )
__global__ void final_kernel(const float* __restrict__ u, const float* __restrict__ v,
                             const float* __restrict__ nx, const float* __restrict__ nmu,
                             const float* __restrict__ bx, const float* __restrict__ bmu,
                             const float* __restrict__ lmbda_p, const float* __restrict__ scale_p,
                             float* __restrict__ out) {
    __shared__ float Us[32][36];
    __shared__ float Vs[32][36];
    const int tid = threadIdx.x;               // 256
    const int tx = tid & 15, ty = tid >> 4;    // 16 x 16, 2x2 micro-tile
    const int b0 = blockIdx.y * 32, c0 = blockIdx.x * 32;
    float acc[2][2] = {};

    for (int k0 = 0; k0 < D_DIM; k0 += 32) {
        for (int i = tid; i < 32 * 32; i += 256) {
            int mm = i >> 5, kk = i & 31;
            Us[kk][mm] = u[(b0 + mm) * D_DIM + k0 + kk];
            int c = c0 + mm;
            Vs[kk][mm] = (c < C_DIM) ? v[c * D_DIM + k0 + kk] : 0.f;
        }
        __syncthreads();
#pragma unroll
        for (int kk = 0; kk < 32; ++kk) {
            float a0 = Us[kk][ty * 2],     a1 = Us[kk][ty * 2 + 1];
            float v0 = Vs[kk][tx * 2],     v1 = Vs[kk][tx * 2 + 1];
            acc[0][0] = fmaf(a0, v0, acc[0][0]);
            acc[0][1] = fmaf(a0, v1, acc[0][1]);
            acc[1][0] = fmaf(a1, v0, acc[1][0]);
            acc[1][1] = fmaf(a1, v1, acc[1][1]);
        }
        __syncthreads();
    }

    const float lm = *lmbda_p, sc = *scale_p;
#pragma unroll
    for (int i = 0; i < 2; ++i) {
        int b = b0 + ty * 2 + i;
#pragma unroll
        for (int j = 0; j < 2; ++j) {
            int c = c0 + tx * 2 + j;
            if (c < C_DIM) {
                float quad = nx[b] + nmu[c] - 2.f * acc[i][j] + EPSF;
                quad = fmaxf(quad, 0.f);
                float bd = bx[b] - bmu[c];
                out[b * C_DIM + c] = -sc * (sqrtf(quad) + lm * sqrtf(fmaf(bd, bd, EPSF)));
            }
        }
    }
}

extern "C" void kernel_launch(void* const* d_in, const int* in_sizes, int n_in,
                              void* d_out, int out_size, void* d_ws, size_t ws_size,
                              hipStream_t stream) {
    const float* x     = (const float*)d_in[0];   // [128,1024]
    const float* mu    = (const float*)d_in[1];   // [1000,1024]
    const float* beta  = (const float*)d_in[2];   // [1024]
    const float* L     = (const float*)d_in[3];   // [1024,1024]
    const float* lmbda = (const float*)d_in[4];   // [1]
    const float* scale = (const float*)d_in[5];   // [1]
    float* out = (float*)d_out;                   // [128,1000]

    float* ws  = (float*)d_ws;
    float* u   = ws;                               // 128*1024
    float* v   = u + B_DIM * D_DIM;                // 1000*1024
    float* nx  = v + C_DIM * D_DIM;                // 128
    float* nmu = nx + B_DIM;                       // 1000
    float* bx  = nmu + C_DIM;                      // 128
    float* bmu = bx + B_DIM;                       // 1000
    // total: ~4.63 MB of workspace

    dim3 blk(256);
    // v = mu @ tril(L)   [1000,1024] x [1024,1024]
    gemm_tril<64, 64, 16><<<dim3(16, 16), blk, 0, stream>>>(mu, L, v, C_DIM);
    // u = x @ tril(L)    [128,1024]  x [1024,1024]
    gemm_tril<64, 64, 16><<<dim3(16, 2), blk, 0, stream>>>(x, L, u, B_DIM);
    // row norms + beta dots
    row_aux<<<dim3(C_DIM), blk, 0, stream>>>(mu, v, beta, nmu, bmu);
    row_aux<<<dim3(B_DIM), blk, 0, stream>>>(x, u, beta, nx, bx);
    // fused cross-GEMM + epilogue
    final_kernel<<<dim3(32, 4), blk, 0, stream>>>(u, v, nx, nmu, bx, bmu,
                                                  lmbda, scale, out);
}

// Round 2
// 109.150 us; speedup vs baseline: 4.0383x; 4.0383x over previous
//
#include <hip/hip_runtime.h>
#include <hip/hip_bf16.h>

#define D_DIM 1024
#define B_DIM 128
#define C_DIM 1000
#define M_ALL 1152   // 128 x-rows + 1000 mu-rows + 24 zero-pad rows
#define EPSF 1e-6f

typedef __attribute__((ext_vector_type(8))) short short8;   // 8 bf16 = 4 VGPRs
typedef __attribute__((ext_vector_type(4))) float f32x4;

static __device__ __forceinline__ unsigned short f2bf(float f) {
    union { float f; unsigned int u; } v; v.f = f;
    unsigned int u = v.u;
    u += 0x7fffu + ((u >> 16) & 1u);   // round-to-nearest-even
    return (unsigned short)(u >> 16);
}
static __device__ __forceinline__ float bf2f(unsigned short s) {
    union { unsigned int u; float f; } v; v.u = ((unsigned int)s) << 16;
    return v.f;
}

// A_bf[1152][1024] bf16: rows 0..127 = x, 128..1127 = mu, 1128..1151 = 0
__global__ void pack_A(const float* __restrict__ x, const float* __restrict__ mu,
                       unsigned short* __restrict__ A_bf) {
    int idx = blockIdx.x * 256 + threadIdx.x;   // one float4 per thread
    int e = idx * 4;
    int row = e >> 10, col = e & 1023;
    float4 v;
    if (row < B_DIM)              v = *(const float4*)(x + row * D_DIM + col);
    else if (row < B_DIM + C_DIM) v = *(const float4*)(mu + (row - B_DIM) * D_DIM + col);
    else                          v = make_float4(0.f, 0.f, 0.f, 0.f);
    ushort4 o;
    o.x = f2bf(v.x); o.y = f2bf(v.y); o.z = f2bf(v.z); o.w = f2bf(v.w);
    *(ushort4*)(A_bf + e) = o;
}

// LT[n][k] = (k >= n) ? bf16(L[k][n]) : 0   — B^T layout for the MFMA GEMM
__global__ void pack_LT(const float* __restrict__ L, unsigned short* __restrict__ LT) {
    __shared__ unsigned short tile[64][65];
    const int tid = threadIdx.x;                 // 256
    const int k0 = blockIdx.y * 64, n0 = blockIdx.x * 64;
    const int tn = tid & 63, tq = tid >> 6;      // tq in 0..3
#pragma unroll
    for (int i = 0; i < 16; ++i) {
        int kk = tq + i * 4;
        int k = k0 + kk, n = n0 + tn;
        float v = (k >= n) ? L[k * D_DIM + n] : 0.f;   // coalesced in n
        tile[tn][kk] = f2bf(v);
    }
    __syncthreads();
#pragma unroll
    for (int i = 0; i < 16; ++i) {
        int nn = tq + i * 4;
        LT[(n0 + nn) * D_DIM + k0 + tn] = tile[nn][tn];  // coalesced in k
    }
}

// C[m][n] = sum_k A[m][k] * BT[n][k], triangular K-skip (BT zero for k < n).
// 64x64 block tile, 4 waves in 2x2, each wave 32x32 via 2x2 mfma_16x16x32.
__global__ __launch_bounds__(256)
void gemm_bt_tri(const unsigned short* __restrict__ A, const unsigned short* __restrict__ BT,
                 unsigned short* __restrict__ Cbf) {
    __shared__ unsigned short As[64][72];   // stride 144 B: 16B-aligned rows
    __shared__ unsigned short Bs[64][72];
    const int tid = threadIdx.x;
    const int m0 = blockIdx.y * 64, n0 = blockIdx.x * 64;
    const int wave = tid >> 6, lane = tid & 63;
    const int wm = (wave & 1) * 32, wn = (wave >> 1) * 32;
    const int lrow = lane & 15, q = lane >> 4;
    f32x4 acc[2][2] = {};

    for (int k0 = n0; k0 < D_DIM; k0 += 64) {   // tri-skip: k < n0 is all-zero in BT
#pragma unroll
        for (int c = tid; c < 512; c += 256) {  // 64 rows x 8 chunks of 8 bf16
            int r = c >> 3, s = (c & 7) * 8;
            *(short8*)&As[r][s] = *(const short8*)(A  + (m0 + r) * D_DIM + k0 + s);
            *(short8*)&Bs[r][s] = *(const short8*)(BT + (n0 + r) * D_DIM + k0 + s);
        }
        __syncthreads();
#pragma unroll
        for (int ks = 0; ks < 64; ks += 32) {
            short8 a0 = *(const short8*)&As[wm +      lrow][ks + q * 8];
            short8 a1 = *(const short8*)&As[wm + 16 + lrow][ks + q * 8];
            short8 b0 = *(const short8*)&Bs[wn +      lrow][ks + q * 8];
            short8 b1 = *(const short8*)&Bs[wn + 16 + lrow][ks + q * 8];
            acc[0][0] = __builtin_amdgcn_mfma_f32_16x16x32_bf16(a0, b0, acc[0][0], 0, 0, 0);
            acc[0][1] = __builtin_amdgcn_mfma_f32_16x16x32_bf16(a0, b1, acc[0][1], 0, 0, 0);
            acc[1][0] = __builtin_amdgcn_mfma_f32_16x16x32_bf16(a1, b0, acc[1][0], 0, 0, 0);
            acc[1][1] = __builtin_amdgcn_mfma_f32_16x16x32_bf16(a1, b1, acc[1][1], 0, 0, 0);
        }
        __syncthreads();
    }
    // C/D layout: col = lane&15, row = (lane>>4)*4 + reg
#pragma unroll
    for (int mi = 0; mi < 2; ++mi)
#pragma unroll
    for (int ni = 0; ni < 2; ++ni) {
        int n = n0 + wn + ni * 16 + lrow;
        int mb = m0 + wm + mi * 16 + q * 4;
#pragma unroll
        for (int r = 0; r < 4; ++r)
            Cbf[(mb + r) * D_DIM + n] = f2bf(acc[mi][ni][r]);
    }
}

// Per row m: nrm[m] = ||P_m||^2 + eps*||A_m||^2 ;  bdot[m] = beta . A_m
__global__ void row_aux(const float* __restrict__ A, const unsigned short* __restrict__ P,
                        const float* __restrict__ beta,
                        float* __restrict__ nrm, float* __restrict__ bdot) {
    const int m = blockIdx.x, tid = threadIdx.x;   // 256 threads x 4 elems = 1024
    const float4  a  = *(const float4*)(A + m * D_DIM + tid * 4);
    const ushort4 pu = *(const ushort4*)(P + m * D_DIM + tid * 4);
    const float4  bt = *(const float4*)(beta + tid * 4);
    float p0 = bf2f(pu.x), p1 = bf2f(pu.y), p2 = bf2f(pu.z), p3 = bf2f(pu.w);
    float sp = p0*p0 + p1*p1 + p2*p2 + p3*p3;
    float sa = a.x*a.x + a.y*a.y + a.z*a.z + a.w*a.w;
    float sb = bt.x*a.x + bt.y*a.y + bt.z*a.z + bt.w*a.w;
#pragma unroll
    for (int off = 32; off > 0; off >>= 1) {
        sp += __shfl_down(sp, off);
        sa += __shfl_down(sa, off);
        sb += __shfl_down(sb, off);
    }
    __shared__ float red[3][4];
    int lane = tid & 63, wid = tid >> 6;
    if (lane == 0) { red[0][wid] = sp; red[1][wid] = sa; red[2][wid] = sb; }
    __syncthreads();
    if (tid == 0) {
        float p = red[0][0] + red[0][1] + red[0][2] + red[0][3];
        float a2 = red[1][0] + red[1][1] + red[1][2] + red[1][3];
        float b2 = red[2][0] + red[2][1] + red[2][2] + red[2][3];
        nrm[m]  = fmaf(EPSF, a2, p);
        bdot[m] = b2;
    }
}

// out[b,c] = -scale*( sqrt(nx[b]+nmu[c]-2*u_b.v_c+eps) + lmbda*sqrt((bx[b]-bmu[c])^2+eps) )
// 32x32 block tile, 4 waves in 2x2, each wave one 16x16 mfma acc. Fused epilogue.
__global__ __launch_bounds__(256)
void gemm_cross(const unsigned short* __restrict__ U, const unsigned short* __restrict__ V,
                const float* __restrict__ nx, const float* __restrict__ nmu,
                const float* __restrict__ bx, const float* __restrict__ bmu,
                const float* __restrict__ lmbda_p, const float* __restrict__ scale_p,
                float* __restrict__ out) {
    __shared__ unsigned short Us[32][72];
    __shared__ unsigned short Vs[32][72];
    const int tid = threadIdx.x;
    const int b0 = blockIdx.y * 32, c0 = blockIdx.x * 32;
    const int wave = tid >> 6, lane = tid & 63;
    const int wm = (wave & 1) * 16, wn = (wave >> 1) * 16;
    const int lrow = lane & 15, q = lane >> 4;
    f32x4 acc = {};

    for (int k0 = 0; k0 < D_DIM; k0 += 64) {
        {   // 32 rows x 8 chunks = 256 = one chunk per thread
            int r = tid >> 3, s = (tid & 7) * 8;
            *(short8*)&Us[r][s] = *(const short8*)(U + (b0 + r) * D_DIM + k0 + s);
            *(short8*)&Vs[r][s] = *(const short8*)(V + (c0 + r) * D_DIM + k0 + s);
        }
        __syncthreads();
#pragma unroll
        for (int ks = 0; ks < 64; ks += 32) {
            short8 a = *(const short8*)&Us[wm + lrow][ks + q * 8];
            short8 b = *(const short8*)&Vs[wn + lrow][ks + q * 8];
            acc = __builtin_amdgcn_mfma_f32_16x16x32_bf16(a, b, acc, 0, 0, 0);
        }
        __syncthreads();
    }
    const float lm = *lmbda_p, sc = *scale_p;
    int c = c0 + wn + lrow;
    if (c < C_DIM) {
        float nm = nmu[c], bm = bmu[c];
#pragma unroll
        for (int r = 0; r < 4; ++r) {
            int b = b0 + wm + q * 4 + r;
            float quad = nx[b] + nm - 2.f * acc[r] + EPSF;
            quad = fmaxf(quad, 0.f);
            float bd = bx[b] - bm;
            out[b * C_DIM + c] = -sc * (sqrtf(quad) + lm * sqrtf(fmaf(bd, bd, EPSF)));
        }
    }
}

extern "C" void kernel_launch(void* const* d_in, const int* in_sizes, int n_in,
                              void* d_out, int out_size, void* d_ws, size_t ws_size,
                              hipStream_t stream) {
    const float* x     = (const float*)d_in[0];   // [128,1024]
    const float* mu    = (const float*)d_in[1];   // [1000,1024]
    const float* beta  = (const float*)d_in[2];   // [1024]
    const float* L     = (const float*)d_in[3];   // [1024,1024]
    const float* lmbda = (const float*)d_in[4];
    const float* scale = (const float*)d_in[5];
    float* out = (float*)d_out;                   // [128,1000]

    char* ws = (char*)d_ws;
    unsigned short* A_bf  = (unsigned short*)ws;                     // 1152*1024*2 = 2359296 B
    unsigned short* LT_bf = (unsigned short*)(ws + 2359296);         // 1024*1024*2 = 2097152 B
    unsigned short* uv_bf = (unsigned short*)(ws + 2359296 + 2097152);   // 1152*1024*2
    float* fws = (float*)(ws + 2359296 + 2097152 + 2359296);
    float* nx  = fws;            // 128
    float* nmu = fws + 128;      // 1000
    float* bx  = fws + 1128;     // 128
    float* bmu = fws + 1256;     // 1000
    // total ws use: ~6.83 MB

    dim3 blk(256);
    pack_A <<<1152, blk, 0, stream>>>(x, mu, A_bf);
    pack_LT<<<dim3(16, 16), blk, 0, stream>>>(L, LT_bf);
    // uv = [x;mu;0] @ tril(L)  -> bf16 [1152][1024]
    gemm_bt_tri<<<dim3(16, 18), blk, 0, stream>>>(A_bf, LT_bf, uv_bf);
    row_aux<<<dim3(B_DIM), blk, 0, stream>>>(x,  uv_bf,                beta, nx,  bx);
    row_aux<<<dim3(C_DIM), blk, 0, stream>>>(mu, uv_bf + B_DIM * D_DIM, beta, nmu, bmu);
    // fused cross-GEMM + epilogue; V rows c>=1000 hit the zero-pad rows of uv_bf
    gemm_cross<<<dim3(32, 4), blk, 0, stream>>>(uv_bf, uv_bf + B_DIM * D_DIM,
                                                nx, nmu, bx, bmu, lmbda, scale, out);
}